// Round 5
// baseline (499.501 us; speedup 1.0000x reference)
//
#include <hip/hip_runtime.h>
#include <float.h>

#define D_DIM 768
#define K_DIM 500
#define NDT   24          // 768 / 32 D-tiles
#define BM    128
#define NTH   512

typedef _Float16 f16x8 __attribute__((ext_vector_type(8)));
typedef float    f32x4 __attribute__((ext_vector_type(4)));

// ws layout:
//   0        : cnorm   float[512]                 (2 KB)
//   4096     : partial double[16*512]             (64 KB)
//   131072   : BpH     _Float16[24*512*32]        (768 KB)
//   917504   : BpL     _Float16[24*512*32]        (768 KB)

// ---------------- cnorm prep (exact, fp64) ----------------
__global__ void cnorm_partial_kernel(const float* __restrict__ C,
                                     double* __restrict__ partial, int K) {
    const int k = threadIdx.x;
    const int w = blockIdx.x;    // 0..15
    double s = 0.0;
    if (k < K) {
        const int d0 = w * (D_DIM / 16);
        for (int d = d0; d < d0 + (D_DIM / 16); ++d) {
            const float c = C[(size_t)d * K + k];
            s = fma((double)c, (double)c, s);
        }
    }
    partial[w * 512 + k] = s;
}

__global__ void cnorm_finish_kernel(const double* __restrict__ partial,
                                    float* __restrict__ cnorm, int K) {
    const int k = threadIdx.x;
    if (k < K) {
        double s = 0.0;
        for (int w = 0; w < 16; ++w) s += partial[w * 512 + k];
        cnorm[k] = (float)s;
    } else {
        cnorm[k] = FLT_MAX;
    }
}

// ---------------- pack C into fragment-ready f16 hi/lo planes ----------------
__global__ void packB_kernel(const float* __restrict__ C,
                             _Float16* __restrict__ BpH,
                             _Float16* __restrict__ BpL) {
    const int idx = blockIdx.x * 256 + threadIdx.x;   // 0..12287
    const int col = idx & 511;
    const int dt  = idx >> 9;                         // 0..23
    f16x8 h[4], l[4];
    #pragma unroll
    for (int c = 0; c < 4; ++c)
        #pragma unroll
        for (int j = 0; j < 8; ++j) {
            const int k = c * 8 + j;
            const float v = (col < K_DIM)
                          ? C[(size_t)(dt * 32 + k) * K_DIM + col] : 0.0f;
            const _Float16 hh = (_Float16)v;
            h[c][j] = hh;
            l[c][j] = (_Float16)(v - (float)hh);
        }
    f16x8* dH = (f16x8*)(BpH + ((size_t)dt * 512 + col) * 32);
    f16x8* dL = (f16x8*)(BpL + ((size_t)dt * 512 + col) * 32);
    #pragma unroll
    for (int c = 0; c < 4; ++c) { dH[c] = h[c]; dL[c] = l[c]; }
}

// ------------- main: barrier-free fp16-split MFMA + fused argmin -------------
__launch_bounds__(NTH, 2)
__global__ void assign_kernel(const float* __restrict__ feat,
                              const _Float16* __restrict__ BpH,
                              const _Float16* __restrict__ BpL,
                              const float* __restrict__ cnorm,
                              int* __restrict__ out,
                              int T) {
    __shared__ float red_v[BM * 4];   // epilogue scratch only
    __shared__ int   red_i[BM * 4];

    const int tid  = threadIdx.x;
    const int wave = tid >> 6;
    const int lane = tid & 63;
    const int wm   = wave >> 2;   // 0..1  (64-row slice)
    const int wn   = wave & 3;    // 0..3  (64-col slice per 256-col half)
    const int l15  = lane & 15;
    const int kg   = lane >> 4;   // 0..3  (k-group)
    const int R0   = blockIdx.x * BM;

    // per-lane A fragment pointers (row clamped; dup rows are discarded at write)
    const float* ap0; const float* ap1; const float* ap2; const float* ap3;
    {
        int r0 = R0 + wm * 64 + 0 * 16 + l15;  r0 = r0 < T ? r0 : T - 1;
        int r1 = R0 + wm * 64 + 1 * 16 + l15;  r1 = r1 < T ? r1 : T - 1;
        int r2 = R0 + wm * 64 + 2 * 16 + l15;  r2 = r2 < T ? r2 : T - 1;
        int r3 = R0 + wm * 64 + 3 * 16 + l15;  r3 = r3 < T ? r3 : T - 1;
        ap0 = feat + (size_t)r0 * D_DIM + kg * 8;
        ap1 = feat + (size_t)r1 * D_DIM + kg * 8;
        ap2 = feat + (size_t)r2 * D_DIM + kg * 8;
        ap3 = feat + (size_t)r3 * D_DIM + kg * 8;
    }

    // B fragment base: col = wn*64 + l15, k-chunk kg
    const _Float16* bpH = BpH + ((size_t)(wn * 64 + l15)) * 32 + kg * 8;
    const _Float16* bpL = BpL + ((size_t)(wn * 64 + l15)) * 32 + kg * 8;

    f32x4 acc[4][8];
    #pragma unroll
    for (int m = 0; m < 4; ++m)
        #pragma unroll
        for (int n = 0; n < 8; ++n) acc[m][n] = (f32x4){0.f, 0.f, 0.f, 0.f};

    // ---- prologue: prefetch raw A for dt = 0
    float4 n0[4], n1[4];
    n0[0] = *(const float4*)(ap0);     n1[0] = *(const float4*)(ap0 + 4);
    n0[1] = *(const float4*)(ap1);     n1[1] = *(const float4*)(ap1 + 4);
    n0[2] = *(const float4*)(ap2);     n1[2] = *(const float4*)(ap2 + 4);
    n0[3] = *(const float4*)(ap3);     n1[3] = *(const float4*)(ap3 + 4);

    for (int dt = 0; dt < NDT; ++dt) {
        const size_t bo = (size_t)dt * 16384;   // dt*512*32

        // ---- convert prefetched raw A -> frags (VALU covers B L2 latency)
        f16x8 aH[4], aL[4];
        #pragma unroll
        for (int m = 0; m < 4; ++m) {
            const float fa[8] = {n0[m].x, n0[m].y, n0[m].z, n0[m].w,
                                 n1[m].x, n1[m].y, n1[m].z, n1[m].w};
            #pragma unroll
            for (int j = 0; j < 8; ++j) {
                const _Float16 hh = (_Float16)fa[j];
                aH[m][j] = hh;
                aL[m][j] = (_Float16)(fa[j] - (float)hh);
            }
        }

        // ---- prefetch raw A for dt+1 (HBM latency hidden under this dt's MFMAs)
        if (dt + 1 < NDT) {
            const int o = (dt + 1) * 32;
            n0[0] = *(const float4*)(ap0 + o);  n1[0] = *(const float4*)(ap0 + o + 4);
            n0[1] = *(const float4*)(ap1 + o);  n1[1] = *(const float4*)(ap1 + o + 4);
            n0[2] = *(const float4*)(ap2 + o);  n1[2] = *(const float4*)(ap2 + o + 4);
            n0[3] = *(const float4*)(ap3 + o);  n1[3] = *(const float4*)(ap3 + o + 4);
        }

        // ---- B direct from L2-resident packed planes + MFMA, per 256-col half
        #pragma unroll
        for (int half = 0; half < 2; ++half) {
            const size_t hb = bo + (size_t)half * 8192;
            f16x8 bH[4], bL[4];
            #pragma unroll
            for (int nh = 0; nh < 4; ++nh) {
                bH[nh] = *(const f16x8*)(bpH + hb + nh * 512);
                bL[nh] = *(const f16x8*)(bpL + hb + nh * 512);
            }
            #pragma unroll
            for (int nh = 0; nh < 4; ++nh) {
                #pragma unroll
                for (int m = 0; m < 4; ++m) {
                    f32x4 a = acc[m][half * 4 + nh];
                    a = __builtin_amdgcn_mfma_f32_16x16x32_f16(aH[m], bH[nh], a, 0, 0, 0);
                    a = __builtin_amdgcn_mfma_f32_16x16x32_f16(aL[m], bH[nh], a, 0, 0, 0);
                    a = __builtin_amdgcn_mfma_f32_16x16x32_f16(aH[m], bL[nh], a, 0, 0, 0);
                    acc[m][half * 4 + nh] = a;
                }
            }
        }
    }

    // ---------------- epilogue: fused argmin ----------------
    float cn[8];
    #pragma unroll
    for (int n = 0; n < 8; ++n) {
        const int colg = (n >> 2) * 256 + wn * 64 + (n & 3) * 16 + l15;
        cn[n] = cnorm[colg];
    }

    #pragma unroll
    for (int m = 0; m < 4; ++m) {
        #pragma unroll
        for (int r = 0; r < 4; ++r) {
            float best = cn[0] - 2.0f * acc[m][0][r];
            int   bi   = wn * 64 + l15;
            #pragma unroll
            for (int n = 1; n < 8; ++n) {
                const int col = (n >> 2) * 256 + wn * 64 + (n & 3) * 16 + l15;
                const float s = cn[n] - 2.0f * acc[m][n][r];
                if (s < best || (s == best && col < bi)) { best = s; bi = col; }
            }
            #pragma unroll
            for (int msk = 1; msk < 16; msk <<= 1) {
                const float ov = __shfl_xor(best, msk, 64);
                const int   oi = __shfl_xor(bi,   msk, 64);
                if (ov < best || (ov == best && oi < bi)) { best = ov; bi = oi; }
            }
            if (l15 == 0) {
                const int rl = wm * 64 + m * 16 + kg * 4 + r;
                red_v[rl * 4 + wn] = best;
                red_i[rl * 4 + wn] = bi;
            }
        }
    }
    __syncthreads();

    if (tid < BM) {
        float bv = red_v[tid * 4];
        int   bi = red_i[tid * 4];
        #pragma unroll
        for (int w = 1; w < 4; ++w) {
            const float v = red_v[tid * 4 + w];
            const int   i = red_i[tid * 4 + w];
            if (v < bv || (v == bv && i < bi)) { bv = v; bi = i; }
        }
        const int r = R0 + tid;
        if (r < T) out[r] = bi;
    }
}

extern "C" void kernel_launch(void* const* d_in, const int* in_sizes, int n_in,
                              void* d_out, int out_size, void* d_ws, size_t ws_size,
                              hipStream_t stream) {
    const float* feat = (const float*)d_in[0];
    const float* C    = (const float*)d_in[1];
    int* out          = (int*)d_out;
    const int T = in_sizes[0] / D_DIM;   // 100000
    const int K = in_sizes[1] / D_DIM;   // 500

    float*     cnorm   = (float*)d_ws;
    double*    partial = (double*)((char*)d_ws + 4096);
    _Float16*  BpH     = (_Float16*)((char*)d_ws + 131072);
    _Float16*  BpL     = (_Float16*)((char*)d_ws + 917504);

    hipLaunchKernelGGL(cnorm_partial_kernel, dim3(16), dim3(512), 0, stream,
                       C, partial, K);
    hipLaunchKernelGGL(cnorm_finish_kernel, dim3(1), dim3(512), 0, stream,
                       partial, cnorm, K);
    hipLaunchKernelGGL(packB_kernel, dim3(48), dim3(256), 0, stream,
                       C, BpH, BpL);

    const int grid = (T + BM - 1) / BM;
    hipLaunchKernelGGL(assign_kernel, dim3(grid), dim3(NTH), 0, stream,
                       feat, BpH, BpL, cnorm, out, T);
}

// Round 6
// 272.245 us; speedup vs baseline: 1.8348x; 1.8348x over previous
//
#include <hip/hip_runtime.h>
#include <float.h>

#define D_DIM 768
#define K_DIM 500
#define NDT   24          // 768 / 32 D-tiles
#define BM    64          // rows per block
#define NTH   256
#define PB_STRIDE 100352  // padded per-half partial stride (rows)

typedef _Float16 f16x8 __attribute__((ext_vector_type(8)));
typedef float    f32x4 __attribute__((ext_vector_type(4)));

// ws layout:
//   0        : cnorm   float[512]                 (2 KB)
//   4096     : partial double[16*512]             (64 KB)
//   131072   : BpH     _Float16[24*512*32]        (768 KB)
//   917504   : BpL     _Float16[24*512*32]        (768 KB)
//   1703936  : pbv     float[2*PB_STRIDE]         (~800 KB)
//   2506752  : pbi     int[2*PB_STRIDE]           (~800 KB)

// ---------------- cnorm prep (exact, fp64) ----------------
__global__ void cnorm_partial_kernel(const float* __restrict__ C,
                                     double* __restrict__ partial, int K) {
    const int k = threadIdx.x;
    const int w = blockIdx.x;    // 0..15
    double s = 0.0;
    if (k < K) {
        const int d0 = w * (D_DIM / 16);
        for (int d = d0; d < d0 + (D_DIM / 16); ++d) {
            const float c = C[(size_t)d * K + k];
            s = fma((double)c, (double)c, s);
        }
    }
    partial[w * 512 + k] = s;
}

__global__ void cnorm_finish_kernel(const double* __restrict__ partial,
                                    float* __restrict__ cnorm, int K) {
    const int k = threadIdx.x;
    if (k < K) {
        double s = 0.0;
        for (int w = 0; w < 16; ++w) s += partial[w * 512 + k];
        cnorm[k] = (float)s;
    } else {
        cnorm[k] = FLT_MAX;
    }
}

// ---------------- pack C into fragment-ready f16 hi/lo planes ----------------
__global__ void packB_kernel(const float* __restrict__ C,
                             _Float16* __restrict__ BpH,
                             _Float16* __restrict__ BpL) {
    const int idx = blockIdx.x * 256 + threadIdx.x;   // 0..12287
    const int col = idx & 511;
    const int dt  = idx >> 9;                         // 0..23
    f16x8 h[4], l[4];
    #pragma unroll
    for (int c = 0; c < 4; ++c)
        #pragma unroll
        for (int j = 0; j < 8; ++j) {
            const int k = c * 8 + j;
            const float v = (col < K_DIM)
                          ? C[(size_t)(dt * 32 + k) * K_DIM + col] : 0.0f;
            const _Float16 hh = (_Float16)v;
            h[c][j] = hh;
            l[c][j] = (_Float16)(v - (float)hh);
        }
    f16x8* dH = (f16x8*)(BpH + ((size_t)dt * 512 + col) * 32);
    f16x8* dL = (f16x8*)(BpL + ((size_t)dt * 512 + col) * 32);
    #pragma unroll
    for (int c = 0; c < 4; ++c) { dH[c] = h[c]; dL[c] = l[c]; }
}

// ------- main: col-split fp16-split MFMA, 64x256 per block, partial argmin ---
__launch_bounds__(NTH, 3)
__global__ void assign_kernel(const float* __restrict__ feat,
                              const _Float16* __restrict__ BpH,
                              const _Float16* __restrict__ BpL,
                              const float* __restrict__ cnorm,
                              float* __restrict__ pbv,
                              int* __restrict__ pbi,
                              int T) {
    // A tiles double-buffered: 2 planes x 2 bufs x 4KB = 16KB
    __shared__ __align__(16) _Float16 AsH[2][BM * 32];
    __shared__ __align__(16) _Float16 AsL[2][BM * 32];
    __shared__ float red_v[BM * 4];
    __shared__ int   red_i[BM * 4];

    const int tid  = threadIdx.x;
    const int wn   = tid >> 6;    // 0..3 (64-col slice)
    const int lane = tid & 63;
    const int l15  = lane & 15;
    const int kg   = lane >> 4;   // 0..3 (k-group)
    const int bid  = blockIdx.x;
    const int half = bid & 1;     // col half: 0 -> cols 0..255, 1 -> 256..511
    const int R0   = (bid >> 1) * BM;

    // A staging map: 4 threads per row, 8 floats each
    const int ar = tid >> 2;            // 0..63
    const int ac = (tid & 3) << 3;      // 0,8,16,24
    const bool arow_ok = (R0 + ar) < T;
    const float* fptr = feat + (size_t)(R0 + ar) * D_DIM + ac;
    const int asl = ((ac >> 3) + (ar >> 1)) & 3;      // slot swizzle for write

    // B fragment base: global col = half*256 + wn*64 + l15, k-chunk kg
    const int colbase = half * 256 + wn * 64 + l15;
    const _Float16* bpH = BpH + (size_t)colbase * 32 + kg * 8;
    const _Float16* bpL = BpL + (size_t)colbase * 32 + kg * 8;

    f32x4 acc[4][4];
    #pragma unroll
    for (int m = 0; m < 4; ++m)
        #pragma unroll
        for (int n = 0; n < 4; ++n) acc[m][n] = (f32x4){0.f, 0.f, 0.f, 0.f};

    // ---- prologue: stage A tile for dt = 0
    {
        float4 v0 = make_float4(0.f, 0.f, 0.f, 0.f), v1 = v0;
        if (arow_ok) {
            v0 = *(const float4*)(fptr);
            v1 = *(const float4*)(fptr + 4);
        }
        const float fa[8] = {v0.x, v0.y, v0.z, v0.w, v1.x, v1.y, v1.z, v1.w};
        f16x8 h, l;
        #pragma unroll
        for (int j = 0; j < 8; ++j) {
            const _Float16 hh = (_Float16)fa[j];
            h[j] = hh; l[j] = (_Float16)(fa[j] - (float)hh);
        }
        ((f16x8*)AsH[0])[ar * 4 + asl] = h;
        ((f16x8*)AsL[0])[ar * 4 + asl] = l;
    }
    __syncthreads();

    for (int dt = 0; dt < NDT; ++dt) {
        const int cur = dt & 1;
        const bool hasNext = (dt + 1) < NDT;

        // ---- A fragments from LDS buf[cur]
        f16x8 aH[4], aL[4];
        #pragma unroll
        for (int m = 0; m < 4; ++m) {
            const int row = m * 16 + l15;
            const int sl  = (kg + (row >> 1)) & 3;
            aH[m] = ((const f16x8*)AsH[cur])[row * 4 + sl];
            aL[m] = ((const f16x8*)AsL[cur])[row * 4 + sl];
        }

        // ---- B fragments direct from L2-resident packed planes (issued FIRST)
        const size_t bo = (size_t)dt * 16384;   // dt*512*32
        f16x8 bH[4], bL[4];
        #pragma unroll
        for (int nh = 0; nh < 4; ++nh) {
            bH[nh] = *(const f16x8*)(bpH + bo + nh * 512);
            bL[nh] = *(const f16x8*)(bpL + bo + nh * 512);
        }

        // ---- next-tile raw A loads issued AFTER B (vmcnt for B won't drain A)
        float4 v0 = make_float4(0.f, 0.f, 0.f, 0.f), v1 = v0;
        if (hasNext && arow_ok) {
            v0 = *(const float4*)(fptr + (dt + 1) * 32);
            v1 = *(const float4*)(fptr + (dt + 1) * 32 + 4);
        }

        // ---- MFMA
        #pragma unroll
        for (int nh = 0; nh < 4; ++nh) {
            #pragma unroll
            for (int m = 0; m < 4; ++m) {
                f32x4 a = acc[m][nh];
                a = __builtin_amdgcn_mfma_f32_16x16x32_f16(aH[m], bH[nh], a, 0, 0, 0);
                a = __builtin_amdgcn_mfma_f32_16x16x32_f16(aL[m], bH[nh], a, 0, 0, 0);
                a = __builtin_amdgcn_mfma_f32_16x16x32_f16(aH[m], bL[nh], a, 0, 0, 0);
                acc[m][nh] = a;
            }
        }

        // ---- convert + stage next A tile into buf[cur^1]
        if (hasNext) {
            const float fa[8] = {v0.x, v0.y, v0.z, v0.w, v1.x, v1.y, v1.z, v1.w};
            f16x8 h, l;
            #pragma unroll
            for (int j = 0; j < 8; ++j) {
                const _Float16 hh = (_Float16)fa[j];
                h[j] = hh; l[j] = (_Float16)(fa[j] - (float)hh);
            }
            ((f16x8*)AsH[cur ^ 1])[ar * 4 + asl] = h;
            ((f16x8*)AsL[cur ^ 1])[ar * 4 + asl] = l;
        }
        __syncthreads();
    }

    // ---------------- epilogue: partial argmin over this block's 256 cols ----
    float cn[4];
    #pragma unroll
    for (int nh = 0; nh < 4; ++nh)
        cn[nh] = cnorm[half * 256 + wn * 64 + nh * 16 + l15];

    #pragma unroll
    for (int m = 0; m < 4; ++m) {
        #pragma unroll
        for (int r = 0; r < 4; ++r) {
            float best = cn[0] - 2.0f * acc[m][0][r];
            int   bi   = colbase;
            #pragma unroll
            for (int nh = 1; nh < 4; ++nh) {
                const int col = colbase + nh * 16;
                const float s = cn[nh] - 2.0f * acc[m][nh][r];
                if (s < best || (s == best && col < bi)) { best = s; bi = col; }
            }
            #pragma unroll
            for (int msk = 1; msk < 16; msk <<= 1) {
                const float ov = __shfl_xor(best, msk, 64);
                const int   oi = __shfl_xor(bi,   msk, 64);
                if (ov < best || (ov == best && oi < bi)) { best = ov; bi = oi; }
            }
            if (l15 == 0) {
                const int rl = m * 16 + kg * 4 + r;
                red_v[rl * 4 + wn] = best;
                red_i[rl * 4 + wn] = bi;
            }
        }
    }
    __syncthreads();

    if (tid < BM) {
        float bv = red_v[tid * 4];
        int   bi = red_i[tid * 4];
        #pragma unroll
        for (int w = 1; w < 4; ++w) {
            const float v = red_v[tid * 4 + w];
            const int   i = red_i[tid * 4 + w];
            if (v < bv || (v == bv && i < bi)) { bv = v; bi = i; }
        }
        const int r = R0 + tid;
        if (r < T) {
            pbv[(size_t)half * PB_STRIDE + r] = bv;
            pbi[(size_t)half * PB_STRIDE + r] = bi;
        }
    }
}

// ---------------- combine the two col-half partials ----------------
__global__ void combine_kernel(const float* __restrict__ pbv,
                               const int* __restrict__ pbi,
                               int* __restrict__ out, int T) {
    const int r = blockIdx.x * 256 + threadIdx.x;
    if (r < T) {
        const float s0 = pbv[r];
        const int   i0 = pbi[r];
        const float s1 = pbv[PB_STRIDE + r];
        const int   i1 = pbi[PB_STRIDE + r];
        // exact tie -> half 0 (lower index), matching numpy argmin
        out[r] = (s1 < s0) ? i1 : i0;
    }
}

extern "C" void kernel_launch(void* const* d_in, const int* in_sizes, int n_in,
                              void* d_out, int out_size, void* d_ws, size_t ws_size,
                              hipStream_t stream) {
    const float* feat = (const float*)d_in[0];
    const float* C    = (const float*)d_in[1];
    int* out          = (int*)d_out;
    const int T = in_sizes[0] / D_DIM;   // 100000
    const int K = in_sizes[1] / D_DIM;   // 500

    float*     cnorm   = (float*)d_ws;
    double*    partial = (double*)((char*)d_ws + 4096);
    _Float16*  BpH     = (_Float16*)((char*)d_ws + 131072);
    _Float16*  BpL     = (_Float16*)((char*)d_ws + 917504);
    float*     pbv     = (float*)((char*)d_ws + 1703936);
    int*       pbi     = (int*)((char*)d_ws + 2506752);

    hipLaunchKernelGGL(cnorm_partial_kernel, dim3(16), dim3(512), 0, stream,
                       C, partial, K);
    hipLaunchKernelGGL(cnorm_finish_kernel, dim3(1), dim3(512), 0, stream,
                       partial, cnorm, K);
    hipLaunchKernelGGL(packB_kernel, dim3(48), dim3(256), 0, stream,
                       C, BpH, BpL);

    const int nrb = (T + BM - 1) / BM;            // row blocks
    hipLaunchKernelGGL(assign_kernel, dim3(nrb * 2), dim3(NTH), 0, stream,
                       feat, BpH, BpL, cnorm, pbv, pbi, T);
    hipLaunchKernelGGL(combine_kernel, dim3((T + 255) / 256), dim3(256), 0, stream,
                       pbv, pbi, out, T);
}